// Round 19
// baseline (125.192 us; speedup 1.0000x reference)
//
#include <hip/hip_runtime.h>
#include <math.h>

// Problem constants: x(256,8192) b,q,e(8192) M(100,8192) out(256,100)
#define NN 8192
#define BB 256
#define CC 100
#define MAX_ITERS 4096
#define T0CAP 192       // phase-A iteration cap (multiple of 4)
#define LISTMAX 16384   // continuation capacity (waves)

__global__ void zero_kernel(unsigned* __restrict__ cnt) { *cnt = 0u; }

// ---------------------------------------------------------------------------
// Shared map-iteration semantics (locked reference flavor, r10):
//   rb=1.0f/b, rob=1.0f/(1-b) hoisted IEEE f32 reciprocals;
//   m' = (m<b ? m*rb : (1-m)*rob); lo=x-e, hi=x+e exact f32 subs;
//   a &= outside-band; kk += a.
// Brent cycle fast-forward is bit-exact AND detection-time-independent:
// survivors of a closed trajectory cycle can never fire, and
// kk += MAX_ITERS - it equals plain counting to the cap (1+it+(4096-it) =
// 4097). Hence phase B may restart Brent fresh at its entry point.
// ---------------------------------------------------------------------------

// Phase A: wave = column x 64 rows, capped at T0CAP iters. Unfinished waves
// write partial kk to kout and push {col|wg, m, actmask} (16 B) to the list.
__global__ __launch_bounds__(256) void fireA_kernel(
    const float* __restrict__ x, const float* __restrict__ bmap,
    const float* __restrict__ qini, const float* __restrict__ eps,
    float* __restrict__ kout, unsigned* __restrict__ cnt,
    uint4* __restrict__ list)
{
    const int j    = blockIdx.x;
    const int lane = threadIdx.x & 63;
    const int wg   = threadIdx.x >> 6;
    const int row  = wg * 64 + lane;

    const float bv  = bmap[j];
    const float qv  = qini[j];
    const float ev  = eps[j];
    const float obv = 1.0f - bv;
    const float rb  = 1.0f / bv;
    const float rob = 1.0f / obv;

    const float xv  = x[(size_t)row * NN + j];
    const float lov = xv - ev;
    const float hiv = xv + ev;

    float m = qv, anchor = qv;
    int   window = 1, steps = 0;
    int   kk = 1;
    bool  a  = (qv != 0.0f);
    bool  cycseen = false;
    bool  finished = false;

    int it = 0;
    while (it < T0CAP) {
        #pragma unroll
        for (int u = 0; u < 4; ++u) {
            const bool  lt = (m < bv);
            const float pa = m * rb;
            const float pb = (1.0f - m) * rob;
            m = lt ? pa : pb;
            cycseen = cycseen || (m == anchor);
            if (++steps == window) { anchor = m; window <<= 1; steps = 0; }
            const bool o = (m < lov) || (m > hiv);
            a = a && o;
            kk += a ? 1 : 0;
        }
        it += 4;
        if (__ballot(a) == 0ull) { finished = true; break; }
        if (cycseen) { kk += a ? (MAX_ITERS - it) : 0; finished = true; break; }
    }

    if (!finished) {
        const unsigned long long mask = __ballot(a);
        unsigned idx = 0;
        if (lane == 0) idx = atomicAdd(cnt, 1u);
        idx = (unsigned)__shfl((int)idx, 0, 64);
        if (idx < LISTMAX) {
            if (lane == 0) {
                uint4 rec;
                rec.x = ((unsigned)j << 2) | (unsigned)wg;
                rec.y = __float_as_uint(m);
                rec.z = (unsigned)(mask & 0xffffffffull);
                rec.w = (unsigned)(mask >> 32);
                list[idx] = rec;
            }
            kout[(size_t)row * NN + j] = (float)kk;   // partial; B continues
            return;
        }
        // overflow fallback: continue inline to MAX_ITERS (same body)
        while (it < MAX_ITERS) {
            #pragma unroll
            for (int u = 0; u < 4; ++u) {
                const bool  lt = (m < bv);
                const float pa = m * rb;
                const float pb = (1.0f - m) * rob;
                m = lt ? pa : pb;
                cycseen = cycseen || (m == anchor);
                if (++steps == window) { anchor = m; window <<= 1; steps = 0; }
                const bool o = (m < lov) || (m > hiv);
                a = a && o;
                kk += a ? 1 : 0;
            }
            it += 4;
            if (__ballot(a) == 0ull) break;
            if (cycseen) { kk += a ? (MAX_ITERS - it) : 0; break; }
        }
    }

    kout[(size_t)row * NN + j] = (float)kk;
}

// Phase B: resume straggler waves. 4 wave-slots per 256-thread block,
// grid-stride over the list. Fresh Brent state (k-exact, see above).
__global__ __launch_bounds__(256) void fireB_kernel(
    const float* __restrict__ x, const float* __restrict__ bmap,
    const float* __restrict__ qini, const float* __restrict__ eps,
    float* __restrict__ kout, const unsigned* __restrict__ cnt,
    const uint4* __restrict__ list)
{
    const unsigned n = min(*cnt, (unsigned)LISTMAX);
    const int lane  = threadIdx.x & 63;
    const int wslot = threadIdx.x >> 6;
    const unsigned slot0   = blockIdx.x * 4 + wslot;
    const unsigned nslots  = gridDim.x * 4;

    for (unsigned idx = slot0; idx < n; idx += nslots) {
        const uint4 rec = list[idx];
        const int j   = (int)(rec.x >> 2);
        const int row = (int)(rec.x & 3u) * 64 + lane;

        const float bv  = bmap[j];
        const float ev  = eps[j];
        const float obv = 1.0f - bv;
        const float rb  = 1.0f / bv;
        const float rob = 1.0f / obv;

        const float xv  = x[(size_t)row * NN + j];
        const float lov = xv - ev;
        const float hiv = xv + ev;

        const unsigned long long mask =
            ((unsigned long long)rec.w << 32) | (unsigned long long)rec.z;
        bool  a  = (mask >> lane) & 1ull;
        int   kk = (int)kout[(size_t)row * NN + j];
        float m  = __uint_as_float(rec.y);
        float anchor = m;
        int   window = 1, steps = 0;
        bool  cycseen = false;

        int it = T0CAP;
        while (it < MAX_ITERS) {
            #pragma unroll
            for (int u = 0; u < 4; ++u) {
                const bool  lt = (m < bv);
                const float pa = m * rb;
                const float pb = (1.0f - m) * rob;
                m = lt ? pa : pb;
                cycseen = cycseen || (m == anchor);
                if (++steps == window) { anchor = m; window <<= 1; steps = 0; }
                const bool o = (m < lov) || (m > hiv);
                a = a && o;
                kk += a ? 1 : 0;
            }
            it += 4;
            if (__ballot(a) == 0ull) break;
            if (cycseen) { kk += a ? (MAX_ITERS - it) : 0; break; }
        }

        kout[(size_t)row * NN + j] = (float)kk;
    }
}

// ---------------------------------------------------------------------------
// Norm kernel (r14/r18 verbatim): blocks 0..255 -> ||k[i]||,
// 256..355 -> ||M[c]||. f64 accumulation; norms[row] = max(sqrt, 1e-8).
// ---------------------------------------------------------------------------
__global__ __launch_bounds__(256) void norm_kernel(
    const float* __restrict__ k, const float* __restrict__ M,
    float* __restrict__ norms)
{
    __shared__ double red[4];
    const int row = blockIdx.x;
    const float* src = (row < BB) ? (k + (size_t)row * NN)
                                  : (M + (size_t)(row - BB) * NN);
    double s = 0.0;
    for (int j = threadIdx.x * 4; j < NN; j += 1024) {
        const float4 v = *(const float4*)(src + j);
        s += (double)v.x * v.x + (double)v.y * v.y
           + (double)v.z * v.z + (double)v.w * v.w;
    }
    #pragma unroll
    for (int off = 32; off; off >>= 1) s += __shfl_down(s, off, 64);
    const int wid = threadIdx.x >> 6, lane = threadIdx.x & 63;
    if (lane == 0) red[wid] = s;
    __syncthreads();
    if (threadIdx.x == 0)
        norms[row] = fmaxf((float)sqrt(red[0] + red[1] + red[2] + red[3]), 1e-8f);
}

// ---------------------------------------------------------------------------
// Logits GEMM kernel (r18 verbatim): block = 8 rows x 5 classes, grid 640.
// ---------------------------------------------------------------------------
#define TR 8
#define TC 5
__global__ __launch_bounds__(256) void logits_gemm(
    const float* __restrict__ k, const float* __restrict__ M,
    const float* __restrict__ norms, float* __restrict__ out)
{
    __shared__ float red[4][TR][TC];

    const int rt  = blockIdx.x / (CC / TC);
    const int ct  = blockIdx.x % (CC / TC);
    const int r0  = rt * TR, c0 = ct * TC;
    const int tid = threadIdx.x;
    const int wid = tid >> 6, lane = tid & 63;

    float acc[TR][TC];
    #pragma unroll
    for (int r = 0; r < TR; ++r)
        #pragma unroll
        for (int c = 0; c < TC; ++c) acc[r][c] = 0.0f;

    for (int s = 0; s < 8; ++s) {
        const int jj = s * 1024 + tid * 4;
        float4 mv[TC];
        #pragma unroll
        for (int c = 0; c < TC; ++c)
            mv[c] = *(const float4*)(M + (size_t)(c0 + c) * NN + jj);
        #pragma unroll
        for (int r = 0; r < TR; ++r) {
            const float4 kv = *(const float4*)(k + (size_t)(r0 + r) * NN + jj);
            #pragma unroll
            for (int c = 0; c < TC; ++c)
                acc[r][c] += kv.x * mv[c].x + kv.y * mv[c].y
                           + kv.z * mv[c].z + kv.w * mv[c].w;
        }
    }

    #pragma unroll
    for (int off = 32; off; off >>= 1)
        #pragma unroll
        for (int r = 0; r < TR; ++r)
            #pragma unroll
            for (int c = 0; c < TC; ++c)
                acc[r][c] += __shfl_down(acc[r][c], off, 64);
    if (lane == 0)
        #pragma unroll
        for (int r = 0; r < TR; ++r)
            #pragma unroll
            for (int c = 0; c < TC; ++c)
                red[wid][r][c] = acc[r][c];
    __syncthreads();

    if (tid < TR * TC) {
        const int r = tid / TC, c = tid % TC;
        const float d = red[0][r][c] + red[1][r][c] + red[2][r][c] + red[3][r][c];
        out[(size_t)(r0 + r) * CC + (c0 + c)] =
            d / (norms[r0 + r] * norms[BB + c0 + c]);
    }
}

// ---------------------------------------------------------------------------
// Single-kernel fire (r15/r17/r18 verbatim, proven 81-83 us): used when ws
// fits the k matrix but not the continuation list.
// ---------------------------------------------------------------------------
__global__ __launch_bounds__(256) void fire_kernel(
    const float* __restrict__ x, const float* __restrict__ bmap,
    const float* __restrict__ qini, const float* __restrict__ eps,
    float* __restrict__ kout)
{
    const int j    = blockIdx.x;
    const int lane = threadIdx.x & 63;
    const int row  = (threadIdx.x & ~63) + lane;

    const float bv  = bmap[j];
    const float qv  = qini[j];
    const float ev  = eps[j];
    const float obv = 1.0f - bv;
    const float rb  = 1.0f / bv;
    const float rob = 1.0f / obv;

    const float xv  = x[(size_t)row * NN + j];
    const float lov = xv - ev;
    const float hiv = xv + ev;

    float m = qv, anchor = qv;
    int   window = 1, steps = 0;
    int   kk = 1;
    bool  a  = (qv != 0.0f);
    bool  cycseen = false;

    int it = 0;
    while (it < MAX_ITERS) {
        #pragma unroll
        for (int u = 0; u < 4; ++u) {
            const bool  lt = (m < bv);
            const float pa = m * rb;
            const float pb = (1.0f - m) * rob;
            m = lt ? pa : pb;
            cycseen = cycseen || (m == anchor);
            if (++steps == window) { anchor = m; window <<= 1; steps = 0; }
            const bool o = (m < lov) || (m > hiv);
            a = a && o;
            kk += a ? 1 : 0;
        }
        it += 4;
        if (__ballot(a) == 0ull) break;
        if (cycseen) { kk += a ? (MAX_ITERS - it) : 0; break; }
    }

    kout[(size_t)row * NN + j] = (float)kk;
}

// ===========================================================================
// FALLBACK: round-10 fused kernel, verbatim (proven green).
// ===========================================================================
__global__ __launch_bounds__(256) void gls_fused_kernel(
    const float* __restrict__ x, const float* __restrict__ bmap,
    const float* __restrict__ qini, const float* __restrict__ eps,
    const float* __restrict__ M, float* __restrict__ out)
{
    __shared__ float k_lds[NN];
    __shared__ double redsh[4];

    const int i   = blockIdx.x;
    const int tid = threadIdx.x;
    const int wid = tid >> 6, lane = tid & 63;

    double sumsq = 0.0;
    for (int s = 0; s < 32; ++s) {
        const int j = tid + 256 * s;
        const float bv = bmap[j];
        const float qv = qini[j];
        const float ev = eps[j];
        const float xv = x[(size_t)i * NN + j];
        const float lov = xv - ev;
        const float hiv = xv + ev;
        const float obv = 1.0f - bv;
        const float rb  = 1.0f / bv;
        const float rob = 1.0f / obv;

        float m  = qv;
        float kk = 1.0f;
        bool  a  = (qv != 0.0f);
        for (int it = 0; a && it < MAX_ITERS; ++it) {
            const bool  lt  = (m < bv);
            const float num = lt ? m  : (1.0f - m);
            const float r   = lt ? rb : rob;
            m = num * r;
            a = (m < lov) || (m > hiv);
            kk += a ? 1.0f : 0.0f;
        }
        k_lds[j] = kk;
        sumsq += (double)kk * (double)kk;
    }

    #pragma unroll
    for (int off = 32; off; off >>= 1) sumsq += __shfl_down(sumsq, off, 64);
    if (lane == 0) redsh[wid] = sumsq;
    __syncthreads();
    const double rn = fmax(sqrt(redsh[0] + redsh[1] + redsh[2] + redsh[3]), 1e-8);

    for (int cc2 = 0; cc2 < 25; ++cc2) {
        const int c = wid * 25 + cc2;
        const float4* Mp = (const float4*)(M + (size_t)c * NN);
        double dot = 0.0, msq = 0.0;
        #pragma unroll 4
        for (int s = 0; s < 32; ++s) {
            const float4 mv = Mp[lane + 64 * s];
            const float4 kv = *(const float4*)(&k_lds[4 * (lane + 64 * s)]);
            dot += (double)kv.x * (double)mv.x + (double)kv.y * (double)mv.y
                 + (double)kv.z * (double)mv.z + (double)kv.w * (double)mv.w;
            msq += (double)mv.x * (double)mv.x + (double)mv.y * (double)mv.y
                 + (double)mv.z * (double)mv.z + (double)mv.w * (double)mv.w;
        }
        #pragma unroll
        for (int off = 32; off; off >>= 1) {
            dot += __shfl_down(dot, off, 64);
            msq += __shfl_down(msq, off, 64);
        }
        if (lane == 0) {
            const double mn = fmax(sqrt(msq), 1e-8);
            out[(size_t)i * CC + c] = (float)(dot / (rn * mn));
        }
    }
}

// ---------------------------------------------------------------------------
extern "C" void kernel_launch(void* const* d_in, const int* in_sizes, int n_in,
                              void* d_out, int out_size, void* d_ws, size_t ws_size,
                              hipStream_t stream) {
    const float* x = (const float*)d_in[0];  // (256, 8192)
    const float* b = (const float*)d_in[1];  // (8192,)
    const float* q = (const float*)d_in[2];  // (8192,)
    const float* e = (const float*)d_in[3];  // (8192,)
    const float* M = (const float*)d_in[4];  // (100, 8192)
    float* out = (float*)d_out;              // (256, 100)

    // ws layout (full): kbuf 8MB | norms (pad 2KB) | cnt (pad 64B) | list
    const size_t kbytes    = (size_t)BB * NN * sizeof(float);
    const size_t off_norms = kbytes;
    const size_t off_cnt   = kbytes + 2048;
    const size_t off_list  = off_cnt + 64;
    const size_t need_cont = off_list + sizeof(uint4) * LISTMAX;
    const size_t need_r18  = kbytes + (BB + CC) * sizeof(float);

    if (ws_size >= need_cont) {
        float*    kbuf  = (float*)d_ws;
        float*    norms = (float*)((char*)d_ws + off_norms);
        unsigned* cnt   = (unsigned*)((char*)d_ws + off_cnt);
        uint4*    list  = (uint4*)((char*)d_ws + off_list);

        zero_kernel<<<dim3(1), dim3(1), 0, stream>>>(cnt);
        fireA_kernel<<<dim3(NN), dim3(256), 0, stream>>>(x, b, q, e, kbuf, cnt, list);
        fireB_kernel<<<dim3(1024), dim3(256), 0, stream>>>(x, b, q, e, kbuf, cnt, list);
        norm_kernel<<<dim3(BB + CC), dim3(256), 0, stream>>>(kbuf, M, norms);
        logits_gemm<<<dim3((BB / TR) * (CC / TC)), dim3(256), 0, stream>>>(kbuf, M, norms, out);
    } else if (ws_size >= need_r18) {
        float* kbuf  = (float*)d_ws;
        float* norms = kbuf + (size_t)BB * NN;
        fire_kernel<<<dim3(NN), dim3(256), 0, stream>>>(x, b, q, e, kbuf);
        norm_kernel<<<dim3(BB + CC), dim3(256), 0, stream>>>(kbuf, M, norms);
        logits_gemm<<<dim3((BB / TR) * (CC / TC)), dim3(256), 0, stream>>>(kbuf, M, norms, out);
    } else {
        gls_fused_kernel<<<dim3(BB), dim3(256), 0, stream>>>(x, b, q, e, M, out);
    }
}